// Round 8
// baseline (57.398 us; speedup 1.0000x reference)
//
#include <hip/hip_runtime.h>
#include <hip/hip_fp16.h>

// LogicLayer: out[b,n] = C0[n] + C1[n]*a + C2[n]*b + C3[n]*a*b,
//   a = x[b, idx_a[n]], b = x[b, idx_b[n]], C = linear combos of softmax(w[n]).
//
// R11: R10 post-mortem — independent co-resident blocks ARE the lever
// (61.8 -> 56.8 with 2 blocks/CU; all in-block scheduling tricks R5-R9 = 0).
// Still nothing saturated (HBM 2.7 TB/s, VALU 9%). Push harder: ROWS=1,
// fp16 row -> 32 KB LDS/block -> 4 blocks/CU co-resident (wave-capped),
// grid=2048, finer generation turnover. Gather count doubles (ds_read_u16
// serves 1 row) but the gather pipe measured ~2-4 us/CU — cheap. Meta
// re-read per row doubles (L2-resident, hidden). Zero persistent state.

#define IN_N   16384
#define OUT_N  16384
#define TPB    512
#define GITERS (OUT_N / 4 / TPB)   // 8 neuron-quads per thread
#define SGRP   (IN_N / 4 / TPB)    // 8 float4 column-chunks per thread

typedef unsigned int u32;
typedef unsigned short u16;
typedef float f4 __attribute__((ext_vector_type(4)));

__global__ __launch_bounds__(256) void prep_kernel(const float* __restrict__ w,
                                                   const int* __restrict__ idx_a,
                                                   const int* __restrict__ idx_b,
                                                   uint2* __restrict__ pcoef,
                                                   uint4* __restrict__ pidx,
                                                   int nout) {
    int n = blockIdx.x * blockDim.x + threadIdx.x;
    if (n < nout) {
        const float4* wn4 = (const float4*)(w + (size_t)n * 16);
        float p[16];
        float4 w0 = wn4[0], w1 = wn4[1], w2 = wn4[2], w3 = wn4[3];
        p[0] = w0.x; p[1] = w0.y; p[2] = w0.z; p[3] = w0.w;
        p[4] = w1.x; p[5] = w1.y; p[6] = w1.z; p[7] = w1.w;
        p[8] = w2.x; p[9] = w2.y; p[10] = w2.z; p[11] = w2.w;
        p[12] = w3.x; p[13] = w3.y; p[14] = w3.z; p[15] = w3.w;
        float m = -1e30f;
#pragma unroll
        for (int i = 0; i < 16; ++i) m = fmaxf(m, p[i]);
        float s = 0.f;
#pragma unroll
        for (int i = 0; i < 16; ++i) { p[i] = __expf(p[i] - m); s += p[i]; }
        float inv = 1.f / s;
#pragma unroll
        for (int i = 0; i < 16; ++i) p[i] *= inv;
        // gates: 0, ab, a-ab, a, b-ab, b, a+b-2ab, a+b-ab,
        //        1-a-b+ab, 1-a-b+2ab, 1-b, 1-b+ab, 1-a, 1-a+ab, 1-ab, 1
        float c0 = p[8] + p[9] + p[10] + p[11] + p[12] + p[13] + p[14] + p[15];
        float c1 = p[2] + p[3] + p[6] + p[7] - p[8] - p[9] - p[12] - p[13];
        float c2 = p[4] + p[5] + p[6] + p[7] - p[8] - p[9] - p[10] - p[11];
        float c3 = p[1] - p[2] - p[4] - 2.f * p[6] - p[7]
                 + p[8] + 2.f * p[9] + p[11] + p[13] - p[14];
        uint2 r;
        r.x = __builtin_bit_cast(u32, __floats2half2_rn(c0, c1));
        r.y = __builtin_bit_cast(u32, __floats2half2_rn(c2, c3));
        pcoef[n] = r;
    }
    if (n < nout / 4) {
        int4 a = ((const int4*)idx_a)[n];
        int4 b = ((const int4*)idx_b)[n];
        uint4 r;
        r.x = (u32)a.x | ((u32)a.y << 16);
        r.y = (u32)a.z | ((u32)a.w << 16);
        r.z = (u32)b.x | ((u32)b.y << 16);
        r.w = (u32)b.z | ((u32)b.w << 16);
        pidx[n] = r;
    }
}

__device__ __forceinline__ float2 h2f(u32 bits) {
    return __half22float2(__builtin_bit_cast(__half2, bits));
}
__device__ __forceinline__ u32 pkh(float a, float b) {
    return __builtin_bit_cast(u32, __floats2half2_rn(a, b));
}
__device__ __forceinline__ float h1f(u16 bits) {
    return __half2float(__builtin_bit_cast(__half, bits));
}

// one neuron, one row. o = a*(c1+c3*b) + (c0+c2*b); c01=(c0,c1), c23=(c2,c3)
__device__ __forceinline__ float neuron1(float a, float b, float2 c01, float2 c23) {
    return fmaf(a, fmaf(c23.y, b, c01.y), fmaf(c23.x, b, c01.x));
}

__global__ __launch_bounds__(TPB) void logic_kernel(const float* __restrict__ x,
                                                    const uint4* __restrict__ pidx,
                                                    const uint4* __restrict__ pcoef,
                                                    float* __restrict__ out) {
    __shared__ u16 hcols[IN_N];   // 32 KB: hcols[i] = fp16 of x[row, i]

    const int t = threadIdx.x;
    const int row = blockIdx.x;

    // Stage one row as fp16.
    const f4* xr = (const f4*)(x + (size_t)row * IN_N);
#pragma unroll
    for (int g = 0; g < SGRP; ++g) {
        int c4 = g * TPB + t;
        f4 v = xr[c4];
        uint2 q;
        q.x = pkh(v.x, v.y);
        q.y = pkh(v.z, v.w);
        *(uint2*)&hcols[c4 * 4] = q;
    }
    __syncthreads();

    // Gather + compute + store. pidx (64 KB) / pcoef (128 KB) are L2-resident.
    f4* op = (f4*)(out + (size_t)row * OUT_N);
#pragma unroll
    for (int k = 0; k < GITERS; ++k) {
        int q = k * TPB + t;
        uint4 idq = pidx[q];
        uint4 cA = pcoef[2 * q + 0];   // coefs for neurons 4q..4q+1
        uint4 cB = pcoef[2 * q + 1];   // coefs for neurons 4q+2..4q+3
        float a0 = h1f(hcols[idq.x & 0xffff]), a1 = h1f(hcols[idq.x >> 16]);
        float a2 = h1f(hcols[idq.y & 0xffff]), a3 = h1f(hcols[idq.y >> 16]);
        float b0 = h1f(hcols[idq.z & 0xffff]), b1 = h1f(hcols[idq.z >> 16]);
        float b2 = h1f(hcols[idq.w & 0xffff]), b3 = h1f(hcols[idq.w >> 16]);
        f4 o;
        o.x = neuron1(a0, b0, h2f(cA.x), h2f(cA.y));
        o.y = neuron1(a1, b1, h2f(cA.z), h2f(cA.w));
        o.z = neuron1(a2, b2, h2f(cB.x), h2f(cB.y));
        o.w = neuron1(a3, b3, h2f(cB.z), h2f(cB.w));
        op[q] = o;
    }
}

extern "C" void kernel_launch(void* const* d_in, const int* in_sizes, int n_in,
                              void* d_out, int out_size, void* d_ws, size_t ws_size,
                              hipStream_t stream) {
    const float* x = (const float*)d_in[0];       // (B, IN) fp32
    const float* w = (const float*)d_in[1];       // (OUT, 16) fp32
    const int* idx_a = (const int*)d_in[2];       // (OUT,) int32
    const int* idx_b = (const int*)d_in[3];       // (OUT,) int32

    const int nout = in_sizes[2];                 // 16384
    const int batch = in_sizes[0] / IN_N;         // 2048

    uint2* pcoef = (uint2*)d_ws;                              // 128 KB
    uint4* pidx  = (uint4*)((char*)d_ws + (size_t)nout * 8);  // 64 KB

    prep_kernel<<<(nout + 255) / 256, 256, 0, stream>>>(w, idx_a, idx_b,
                                                        pcoef, pidx, nout);
    logic_kernel<<<batch, TPB, 0, stream>>>(x, pidx, (const uint4*)pcoef,
                                            (float*)d_out);
}

// Round 9
// 48.581 us; speedup vs baseline: 1.1815x; 1.1815x over previous
//
#include <hip/hip_runtime.h>
#include <hip/hip_fp16.h>

// LogicLayer: out[b,n] = C0[n] + C1[n]*a + C2[n]*b + C3[n]*a*b,
//   a = x[b, idx_a[n]], b = x[b, idx_b[n]], C = linear combos of softmax(w[n]).
//
// R12: R11 post-mortem — 4 blocks/CU neutral (phases align chip-wide).
// FETCH ledger across rounds: nt-LOADS (R6-R8) forced full-x HBM reads
// (FETCH 110-145 MB); plain loads (R9-R11) hit L3 for half of x (67 MB).
// The other half is evicted by OUR OWN out-stream flowing through L3.
// Fix: R10 kernel + nontemporal STORES only (plain loads). Writes bypass
// L2/L3 -> x stays L3-resident -> read phase served from L3, HBM dedicated
// to the write stream. Structure identical to R10 (best, 56.8 us):
// TPB=512, ROWS=2, 64 KB LDS, 2 blocks/CU, zero persistent state.

#define IN_N   16384
#define OUT_N  16384
#define TPB    512
#define ROWS   2
#define GITERS (OUT_N / 4 / TPB)   // 8 neuron-quads per thread
#define SGRP   (IN_N / 4 / TPB)    // 8 column-chunks (4 cols each) per thread

typedef unsigned int u32;
typedef float f4 __attribute__((ext_vector_type(4)));

__global__ __launch_bounds__(256) void prep_kernel(const float* __restrict__ w,
                                                   const int* __restrict__ idx_a,
                                                   const int* __restrict__ idx_b,
                                                   uint2* __restrict__ pcoef,
                                                   uint4* __restrict__ pidx,
                                                   int nout) {
    int n = blockIdx.x * blockDim.x + threadIdx.x;
    if (n < nout) {
        const float4* wn4 = (const float4*)(w + (size_t)n * 16);
        float p[16];
        float4 w0 = wn4[0], w1 = wn4[1], w2 = wn4[2], w3 = wn4[3];
        p[0] = w0.x; p[1] = w0.y; p[2] = w0.z; p[3] = w0.w;
        p[4] = w1.x; p[5] = w1.y; p[6] = w1.z; p[7] = w1.w;
        p[8] = w2.x; p[9] = w2.y; p[10] = w2.z; p[11] = w2.w;
        p[12] = w3.x; p[13] = w3.y; p[14] = w3.z; p[15] = w3.w;
        float m = -1e30f;
#pragma unroll
        for (int i = 0; i < 16; ++i) m = fmaxf(m, p[i]);
        float s = 0.f;
#pragma unroll
        for (int i = 0; i < 16; ++i) { p[i] = __expf(p[i] - m); s += p[i]; }
        float inv = 1.f / s;
#pragma unroll
        for (int i = 0; i < 16; ++i) p[i] *= inv;
        // gates: 0, ab, a-ab, a, b-ab, b, a+b-2ab, a+b-ab,
        //        1-a-b+ab, 1-a-b+2ab, 1-b, 1-b+ab, 1-a, 1-a+ab, 1-ab, 1
        float c0 = p[8] + p[9] + p[10] + p[11] + p[12] + p[13] + p[14] + p[15];
        float c1 = p[2] + p[3] + p[6] + p[7] - p[8] - p[9] - p[12] - p[13];
        float c2 = p[4] + p[5] + p[6] + p[7] - p[8] - p[9] - p[10] - p[11];
        float c3 = p[1] - p[2] - p[4] - 2.f * p[6] - p[7]
                 + p[8] + 2.f * p[9] + p[11] + p[13] - p[14];
        uint2 r;
        r.x = __builtin_bit_cast(u32, __floats2half2_rn(c0, c1));
        r.y = __builtin_bit_cast(u32, __floats2half2_rn(c2, c3));
        pcoef[n] = r;
    }
    if (n < nout / 4) {
        int4 a = ((const int4*)idx_a)[n];
        int4 b = ((const int4*)idx_b)[n];
        uint4 r;
        r.x = (u32)a.x | ((u32)a.y << 16);
        r.y = (u32)a.z | ((u32)a.w << 16);
        r.z = (u32)b.x | ((u32)b.y << 16);
        r.w = (u32)b.z | ((u32)b.w << 16);
        pidx[n] = r;
    }
}

__device__ __forceinline__ float2 h2f(u32 bits) {
    return __half22float2(__builtin_bit_cast(__half2, bits));
}
__device__ __forceinline__ u32 pkh(float a, float b) {
    return __builtin_bit_cast(u32, __floats2half2_rn(a, b));
}

// one neuron, 2 rows packed in one u32 (half2). o = a*(c1+c3*b) + (c0+c2*b)
__device__ __forceinline__ float2 neuron2(u32 a, u32 b, float2 c01, float2 c23) {
    float2 af = h2f(a), bf = h2f(b);
    float2 o;
    o.x = fmaf(af.x, fmaf(c23.y, bf.x, c01.y), fmaf(c23.x, bf.x, c01.x));
    o.y = fmaf(af.y, fmaf(c23.y, bf.y, c01.y), fmaf(c23.x, bf.y, c01.x));
    return o;
}

__global__ __launch_bounds__(TPB) void logic_kernel(const float* __restrict__ x,
                                                    const uint4* __restrict__ pidx,
                                                    const uint4* __restrict__ pcoef,
                                                    float* __restrict__ out) {
    __shared__ u32 cols[IN_N];   // 64 KB: cols[i] = half2(row0,row1) of column i

    const int t = threadIdx.x;
    const int b0 = blockIdx.x * ROWS;

    // Stage 2 rows, fp16 column-interleaved. PLAIN loads: let x live in L3.
    const f4* x0 = (const f4*)(x + (size_t)(b0 + 0) * IN_N);
    const f4* x1 = (const f4*)(x + (size_t)(b0 + 1) * IN_N);
#pragma unroll
    for (int g = 0; g < SGRP; ++g) {
        int c4 = g * TPB + t;
        f4 v0 = x0[c4];
        f4 v1 = x1[c4];
        uint4 q;
        q.x = pkh(v0.x, v1.x);
        q.y = pkh(v0.y, v1.y);
        q.z = pkh(v0.z, v1.z);
        q.w = pkh(v0.w, v1.w);
        *(uint4*)&cols[c4 * 4] = q;
    }
    __syncthreads();

    // Gather + compute + store. pidx/pcoef are L2-resident (64+128 KB shared
    // by all blocks). Stores are NONTEMPORAL: bypass L2/L3 so the out-stream
    // doesn't evict x from the Infinity Cache.
    f4* o0p = (f4*)(out + (size_t)(b0 + 0) * OUT_N);
    f4* o1p = (f4*)(out + (size_t)(b0 + 1) * OUT_N);
#pragma unroll
    for (int k = 0; k < GITERS; ++k) {
        int q = k * TPB + t;
        uint4 idq = pidx[q];
        uint4 cA = pcoef[2 * q + 0];   // coefs for neurons 4q..4q+1
        uint4 cB = pcoef[2 * q + 1];   // coefs for neurons 4q+2..4q+3
        u32 A0 = cols[idq.x & 0xffff], A1 = cols[idq.x >> 16];
        u32 A2 = cols[idq.y & 0xffff], A3 = cols[idq.y >> 16];
        u32 B0 = cols[idq.z & 0xffff], B1 = cols[idq.z >> 16];
        u32 B2 = cols[idq.w & 0xffff], B3 = cols[idq.w >> 16];
        float2 r0 = neuron2(A0, B0, h2f(cA.x), h2f(cA.y));
        float2 r1 = neuron2(A1, B1, h2f(cA.z), h2f(cA.w));
        float2 r2 = neuron2(A2, B2, h2f(cB.x), h2f(cB.y));
        float2 r3 = neuron2(A3, B3, h2f(cB.z), h2f(cB.w));
        f4 o0, o1;
        o0.x = r0.x; o1.x = r0.y;
        o0.y = r1.x; o1.y = r1.y;
        o0.z = r2.x; o1.z = r2.y;
        o0.w = r3.x; o1.w = r3.y;
        __builtin_nontemporal_store(o0, o0p + q);
        __builtin_nontemporal_store(o1, o1p + q);
    }
}

extern "C" void kernel_launch(void* const* d_in, const int* in_sizes, int n_in,
                              void* d_out, int out_size, void* d_ws, size_t ws_size,
                              hipStream_t stream) {
    const float* x = (const float*)d_in[0];       // (B, IN) fp32
    const float* w = (const float*)d_in[1];       // (OUT, 16) fp32
    const int* idx_a = (const int*)d_in[2];       // (OUT,) int32
    const int* idx_b = (const int*)d_in[3];       // (OUT,) int32

    const int nout = in_sizes[2];                 // 16384
    const int batch = in_sizes[0] / IN_N;         // 2048

    uint2* pcoef = (uint2*)d_ws;                              // 128 KB
    uint4* pidx  = (uint4*)((char*)d_ws + (size_t)nout * 8);  // 64 KB

    prep_kernel<<<(nout + 255) / 256, 256, 0, stream>>>(w, idx_a, idx_b,
                                                        pcoef, pidx, nout);
    logic_kernel<<<batch / ROWS, TPB, 0, stream>>>(x, pidx, (const uint4*)pcoef,
                                                   (float*)d_out);
}